// Round 7
// baseline (20988.646 us; speedup 1.0000x reference)
//
#include <hip/hip_runtime.h>
#include <hip/hip_bf16.h>
#include <hip/hip_cooperative_groups.h>

namespace cg = cooperative_groups;

// NS solver: 256x256 periodic, B=8, NC=3 (u,v,density), T outer x 10 inner steps.
// y0 = fp32, dt = fp32, out = fp32 (established R1-R5). Internal state fp32.
//
// R7: cooperative mega-kernel (R6 fixed). R6 aborted on an OOB: grid-stride
// phases used 16 iters/block at 512 blocks = 4x TOTAL -> aperture violation.
// Correct: TOTAL/512/256 = 4 iters, idx = (blk<<10)+(it<<8)+tid.
//
// Phases per inner step (4 grid syncs):
//   P1 advect inb->outb (+write_out of inb every 10th step) [512 blocks]
//   P2 div(outb) + fwd row FFT -> S                          [blocks 0..255]
//   P3 col FFT * invLam/N^2 * inv col FFT (in-place S)       [blocks 0..255]
//   P4 inv row FFT (9 rows, 1 redundant) -> q in LDS; correct outb in place
// S aliases the dead inb V,D fields (R5-proven aliasing): after P1, inb is
// dead; next step's advect only WRITES that bank. ws = 6*TOTAL = 12.58 MB.
// Fallback: if cooperative launch is rejected, replay the R5 5-kernel path.

#define NN 256
#define NM 255
#define FIELD (NN*NN)
#define BATCH 8
#define TOTAL (BATCH*FIELD)
#define TEAMS 8

constexpr float RDX  = 40.743665431525205f;   // N/(2*pi) = 1/DX
constexpr float VISC = 1e-3f;

__device__ __forceinline__ int rev8(int x) { return (int)(__brev((unsigned)x) >> 24); }

__device__ __forceinline__ float decode_dt(const unsigned* dtw) {
  unsigned w = dtw[0];
  float cf = __uint_as_float(w);
  float cb = __uint_as_float((w & 0xFFFFu) << 16);
  bool v32 = (cf > 1e-8f) && (cf < 1.0f);          // NaN-safe
  bool vbf = (cb > 1e-8f) && (cb < 1.0f);
  return v32 ? cf : (vbf ? cb : 1e-3f);
}

// ---------------------------------------------------------------- advection
__device__ __forceinline__ float face_flux(float uf, float cm, float c0,
                                           float cp, float cpp, float hdtdx) {
  float dc = cp - c0;
  float f_low  = (uf >= 0.0f) ? uf*c0 : uf*cp;
  float f_high = uf*0.5f*(c0+cp) - hdtdx*uf*uf*dc;
  float dc_up  = (uf >= 0.0f) ? (c0 - cm) : (cpp - cp);
  float dc_safe = (fabsf(dc) > 1e-12f) ? dc : 1e-12f;
  // van Leer: r=a/b, phi=(r>0)?2r/(1+r):0  ==  (a*b>0)?2a/(a+b):0
  float phi = (dc_up * dc_safe > 0.0f) ? (2.0f*dc_up/(dc_up + dc_safe)) : 0.0f;
  return f_low + phi*(f_high - f_low);
}

__device__ __forceinline__ void advect_cell(
    const float* __restrict__ U, const float* __restrict__ V, const float* __restrict__ D,
    float* __restrict__ Uo, float* __restrict__ Vo, float* __restrict__ Do_,
    int idx, float hdtdx, float dt)
{
  int j = idx & NM;
  int i = (idx >> 8) & NM;
  int base = (idx >> 16) * FIELD;

  const float* Ub = U + base;
  const float* Vb = V + base;
  const float* Db = D + base;

  int im2 = ((i-2)&NM)*NN, im1 = ((i-1)&NM)*NN, i0r = i*NN,
      ip1 = ((i+1)&NM)*NN, ip2 = ((i+2)&NM)*NN;
  int jm2 = (j-2)&NM, jm1 = (j-1)&NM, jp1 = (j+1)&NM, jp2 = (j+2)&NM;

  float u_c  = Ub[i0r+j];
  float u_im2= Ub[im2+j], u_im1 = Ub[im1+j], u_ip1 = Ub[ip1+j], u_ip2 = Ub[ip2+j];
  float u_jm2= Ub[i0r+jm2], u_jm1 = Ub[i0r+jm1], u_jp1 = Ub[i0r+jp1], u_jp2 = Ub[i0r+jp2];
  float v_c  = Vb[i0r+j];
  float v_im2= Vb[im2+j], v_im1 = Vb[im1+j], v_ip1 = Vb[ip1+j], v_ip2 = Vb[ip2+j];
  float v_jm2= Vb[i0r+jm2], v_jm1 = Vb[i0r+jm1], v_jp1 = Vb[i0r+jp1], v_jp2 = Vb[i0r+jp2];
  float d_c  = Db[i0r+j];
  float d_im2= Db[im2+j], d_im1 = Db[im1+j], d_ip1 = Db[ip1+j], d_ip2 = Db[ip2+j];
  float d_jm2= Db[i0r+jm2], d_jm1 = Db[i0r+jm1], d_jp1 = Db[i0r+jp1], d_jp2 = Db[i0r+jp2];

  float ufI0 = 0.5f*(u_c + u_ip1);
  float ufIm = 0.5f*(u_im1 + u_c);
  float vfJ0 = 0.5f*(v_c + v_jp1);
  float vfJm = 0.5f*(v_jm1 + v_c);

  float tu = -(( face_flux(ufI0, u_im1, u_c, u_ip1, u_ip2, hdtdx)
               - face_flux(ufIm, u_im2, u_im1, u_c, u_ip1, hdtdx))
             + ( face_flux(vfJ0, u_jm1, u_c, u_jp1, u_jp2, hdtdx)
               - face_flux(vfJm, u_jm2, u_jm1, u_c, u_jp1, hdtdx))) * RDX;
  float lapu = (u_im1 + u_ip1 + u_jm1 + u_jp1 - 4.0f*u_c) * (RDX*RDX);

  float tv = -(( face_flux(ufI0, v_im1, v_c, v_ip1, v_ip2, hdtdx)
               - face_flux(ufIm, v_im2, v_im1, v_c, v_ip1, hdtdx))
             + ( face_flux(vfJ0, v_jm1, v_c, v_jp1, v_jp2, hdtdx)
               - face_flux(vfJm, v_jm2, v_jm1, v_c, v_jp1, hdtdx))) * RDX;
  float lapv = (v_im1 + v_ip1 + v_jm1 + v_jp1 - 4.0f*v_c) * (RDX*RDX);

  float td = -(( face_flux(ufI0, d_im1, d_c, d_ip1, d_ip2, hdtdx)
               - face_flux(ufIm, d_im2, d_im1, d_c, d_ip1, hdtdx))
             + ( face_flux(vfJ0, d_jm1, d_c, d_jp1, d_jp2, hdtdx)
               - face_flux(vfJm, d_jm2, d_jm1, d_c, d_jp1, hdtdx))) * RDX;

  Uo[idx] = u_c + dt*(tu + VISC*lapu);
  Vo[idx] = v_c + dt*(tv + VISC*lapv);
  Do_[idx] = d_c + dt*td;
}

// ---------------------------------------------------------------- FFT cores
// Forward: in-place radix-2 DIT; input pre-loaded BIT-REVERSED, natural out.
__device__ __forceinline__ void fft256_dit_fwd(float2* __restrict__ A, int lane)
{
  #pragma unroll
  for (int s = 1; s <= 8; ++s) {
    int L = 1 << s, half = L >> 1;
    float angscale = -6.28318530717958647692f / (float)L;
    #pragma unroll
    for (int r = 0; r < 4; ++r) {
      int bfly = lane + (r << 5);
      int q = bfly & (half - 1);
      int g = (bfly >> (s - 1)) << s;
      float sw, cw;
      __sincosf(angscale * (float)q, &sw, &cw);
      float2 a = A[g + q];
      float2 b = A[g + q + half];
      float wbx = cw*b.x - sw*b.y;
      float wby = cw*b.y + sw*b.x;
      A[g + q]        = make_float2(a.x + wbx, a.y + wby);
      A[g + q + half] = make_float2(a.x - wbx, a.y - wby);
    }
    __syncthreads();
  }
}

// Inverse (unnormalized): in-place radix-2 DIF; natural in, BIT-REVERSED out.
__device__ __forceinline__ void fft256_dif_inv(float2* __restrict__ A, int lane)
{
  #pragma unroll
  for (int s = 8; s >= 1; --s) {
    int L = 1 << s, half = L >> 1;
    float angscale = 6.28318530717958647692f / (float)L;
    #pragma unroll
    for (int r = 0; r < 4; ++r) {
      int bfly = lane + (r << 5);
      int q = bfly & (half - 1);
      int g = (bfly >> (s - 1)) << s;
      float sw, cw;
      __sincosf(angscale * (float)q, &sw, &cw);
      float2 a = A[g + q];
      float2 b = A[g + q + half];
      float dx = a.x - b.x, dy = a.y - b.y;
      A[g + q]        = make_float2(a.x + b.x, a.y + b.y);
      A[g + q + half] = make_float2(cw*dx - sw*dy, cw*dy + sw*dx);
    }
    __syncthreads();
  }
}

// ================================================================ coop kernel
__global__ __launch_bounds__(256, 2) void ns_coop(
    const float* __restrict__ y0, const unsigned* __restrict__ dtw,
    float* __restrict__ out, float* __restrict__ ws, int T)
{
  cg::grid_group grid = cg::this_grid();
  const int tid  = threadIdx.x;
  const int blk  = blockIdx.x;          // 0..511
  const bool fftb = (blk < 256);        // FFT-phase blocks
  const int b    = blk >> 5;            // batch (valid for fftb)
  const int row0 = (blk & 31) << 3;     // row/col group base (valid for fftb)
  const int g    = tid >> 5, lane = tid & 31;

  const float dt = decode_dt(dtw);
  const float hdtdx = 0.5f*dt*RDX;

  __shared__ __align__(16) float sbuf[6400];
  float*  qs = sbuf;                    // [9][256]
  float2* Ab = (float2*)(sbuf + 2304);  // [8][256]

  // ---- P0: init state into bank0 (512 blocks x 4 iters x 256 = TOTAL)
  for (int it = 0; it < 4; ++it) {
    int idx = (blk << 10) + (it << 8) + tid;
    ws[idx]           = y0[idx*3];
    ws[TOTAL + idx]   = y0[idx*3+1];
    ws[2*TOTAL + idx] = y0[idx*3+2];
  }
  grid.sync();

  int p = 0;
  for (int step = 0; step < 10*T; ++step) {
    const int t = step / 10, s10 = step - 10*t;
    const float* __restrict__ inb  = ws + p*3*TOTAL;
    float*       __restrict__ outb = ws + (1-p)*3*TOTAL;
    float2* S = (float2*)(ws + p*3*TOTAL + TOTAL);  // aliases dead inb V,D after P1

    // ---- P1: (write_out of state t-1 every 10th step) + advect
    if (s10 == 0 && t > 0) {
      for (int it = 0; it < 4; ++it) {
        int idx = (blk << 10) + (it << 8) + tid;
        int bb = idx >> 16, pos = idx & 65535;
        size_t o = ((size_t)(bb*T + (t-1))*FIELD + pos)*3u;
        out[o]   = inb[idx];
        out[o+1] = inb[TOTAL + idx];
        out[o+2] = inb[2*TOTAL + idx];
      }
    }
    for (int it = 0; it < 4; ++it) {
      int idx = (blk << 10) + (it << 8) + tid;
      advect_cell(inb, inb+TOTAL, inb+2*TOTAL,
                  outb, outb+TOTAL, outb+2*TOTAL, idx, hdtdx, dt);
    }
    grid.sync();

    // ---- P2: div(outb) + forward row FFT -> S (S = dead inb V,D)
    if (fftb) {
      const float* Ug = outb + b*FIELD;
      const float* Vg = outb + TOTAL + b*FIELD;
      int jm1 = (tid - 1) & NM;
      int rj = rev8(tid);
      #pragma unroll
      for (int k = 0; k < 8; ++k) {
        int row = row0 + k, rm1 = (row - 1) & NM;
        float dv = (Ug[row*NN + tid] - Ug[rm1*NN + tid]
                  + Vg[row*NN + tid] - Vg[row*NN + jm1]) * RDX;
        Ab[(k<<8) + rj] = make_float2(dv, 0.0f);
      }
      __syncthreads();
      fft256_dit_fwd(Ab + (g<<8), lane);
      float2* Sb = S + b*FIELD;
      #pragma unroll
      for (int k = 0; k < 8; ++k)
        Sb[(row0 + k)*NN + tid] = Ab[(k<<8) + tid];
    }
    grid.sync();

    // ---- P3: col FFT + invLam/N^2 scale + inv col FFT (col0 == row0)
    if (fftb) {
      float2* Sb = S + b*FIELD;
      #pragma unroll
      for (int k = 0; k < 8; ++k) {
        int idx = tid + (k << 8);
        int i = idx >> 3, c = idx & 7;
        Ab[(c<<8) + rev8(i)] = Sb[i*NN + row0 + c];
      }
      __syncthreads();
      fft256_dit_fwd(Ab + (g<<8), lane);
      int k2 = row0 + g;
      float s2v = __sinf(0.01227184630308512983f * (float)k2);  // pi/256*k
      float l2 = -4.0f * s2v * s2v * (RDX*RDX);
      #pragma unroll
      for (int r = 0; r < 8; ++r) {
        int k1 = lane + (r << 5);
        float s1 = __sinf(0.01227184630308512983f * (float)k1);
        float l1 = -4.0f * s1 * s1 * (RDX*RDX);
        float den = l1 + l2;
        float sc = ((k1 | k2) == 0) ? 0.0f : (1.0f/den);
        sc *= (1.0f/65536.0f);
        float2 v = Ab[(g<<8) + k1];
        Ab[(g<<8) + k1] = make_float2(v.x*sc, v.y*sc);
      }
      __syncthreads();
      fft256_dif_inv(Ab + (g<<8), lane);
      #pragma unroll
      for (int k = 0; k < 8; ++k) {
        int idx = tid + (k << 8);
        int i = idx >> 3, c = idx & 7;
        Sb[i*NN + row0 + c] = Ab[(c<<8) + rev8(i)];
      }
    }
    grid.sync();

    // ---- P4: inv row FFT (rows row0..row0+8, one redundant) + correction
    if (fftb) {
      const float2* Sb = S + b*FIELD;
      int rj = rev8(tid);
      #pragma unroll
      for (int k = 0; k < 8; ++k)
        Ab[(k<<8) + tid] = Sb[(row0 + k)*NN + tid];
      __syncthreads();
      fft256_dif_inv(Ab + (g<<8), lane);
      #pragma unroll
      for (int k = 0; k < 8; ++k)
        qs[(k<<8) + rj] = Ab[(k<<8) + tid].x;   // scatter un-reverse
      __syncthreads();
      // 9th row (wraps at row0=248): full row loaded into team-0's buffer
      int r8 = (row0 + 8) & NM;
      Ab[tid] = Sb[r8*NN + tid];
      __syncthreads();
      fft256_dif_inv(Ab + (g<<8), lane);        // teams 1..7 compute discard
      qs[(8<<8) + rj] = Ab[tid].x;
      __syncthreads();
      float* Ug = outb + b*FIELD;
      float* Vg = outb + TOTAL + b*FIELD;
      int jp1 = (tid + 1) & NM;
      #pragma unroll
      for (int k = 0; k < 8; ++k) {
        int gi = (row0 + k)*NN + tid;
        float q0 = qs[(k<<8) + tid];
        float q1 = qs[((k+1)<<8) + tid];
        float qj = qs[(k<<8) + jp1];
        Ug[gi] -= (q1 - q0)*RDX;
        Vg[gi] -= (qj - q0)*RDX;
      }
    }
    grid.sync();

    p ^= 1;
  }

  // ---- tail: write_out of final state (t = T-1)
  {
    const float* inb = ws + p*3*TOTAL;
    for (int it = 0; it < 4; ++it) {
      int idx = (blk << 10) + (it << 8) + tid;
      int bb = idx >> 16, pos = idx & 65535;
      size_t o = ((size_t)(bb*T + (T-1))*FIELD + pos)*3u;
      out[o]   = inb[idx];
      out[o+1] = inb[TOTAL + idx];
      out[o+2] = inb[2*TOTAL + idx];
    }
  }
}

// ================================================================ fallback
// R5's proven 5-kernel path (used only if cooperative launch is rejected).
__global__ __launch_bounds__(256) void advect_kernel(
    const float* __restrict__ U, const float* __restrict__ V, const float* __restrict__ D,
    float* __restrict__ Uo, float* __restrict__ Vo, float* __restrict__ Do_,
    const unsigned* __restrict__ dtw)
{
  int idx = blockIdx.x*256 + threadIdx.x;
  float dt = decode_dt(dtw);
  advect_cell(U, V, D, Uo, Vo, Do_, idx, 0.5f*dt*RDX, dt);
}

__global__ __launch_bounds__(256) void fft_rows_div(
    const float* __restrict__ U2, const float* __restrict__ V2, float2* __restrict__ S)
{
  __shared__ float2 Ab[TEAMS][NN];
  int tid = threadIdx.x;
  int b = blockIdx.x >> 5;
  int row0 = (blockIdx.x & 31) << 3;
  const float* Ub = U2 + b*FIELD;
  const float* Vb = V2 + b*FIELD;
  int jm1 = (tid - 1) & NM;
  int rj = rev8(tid);
  #pragma unroll
  for (int k = 0; k < 8; ++k) {
    int row = row0 + k, rm1 = (row - 1) & NM;
    float dv = (Ub[row*NN + tid] - Ub[rm1*NN + tid]
              + Vb[row*NN + tid] - Vb[row*NN + jm1]) * RDX;
    Ab[k][rj] = make_float2(dv, 0.0f);
  }
  __syncthreads();
  int g = tid >> 5, lane = tid & 31;
  fft256_dit_fwd(Ab[g], lane);
  float2* Sb = S + b*FIELD;
  #pragma unroll
  for (int k = 0; k < 8; ++k)
    Sb[(row0 + k)*NN + tid] = Ab[k][tid];
}

__global__ __launch_bounds__(256) void fft_cols(float2* __restrict__ S)
{
  __shared__ float2 Ab[TEAMS][NN];
  int tid = threadIdx.x;
  int b = blockIdx.x >> 5;
  int col0 = (blockIdx.x & 31) << 3;
  float2* Sb = S + b*FIELD;
  #pragma unroll
  for (int k = 0; k < 8; ++k) {
    int idx = tid + (k << 8);
    int i = idx >> 3, c = idx & 7;
    Ab[c][rev8(i)] = Sb[i*NN + col0 + c];
  }
  __syncthreads();
  int g = tid >> 5, lane = tid & 31;
  fft256_dit_fwd(Ab[g], lane);
  int k2 = col0 + g;
  float s2 = __sinf(0.01227184630308512983f * (float)k2);
  float l2 = -4.0f * s2 * s2 * (RDX*RDX);
  #pragma unroll
  for (int r = 0; r < 8; ++r) {
    int k1 = lane + (r << 5);
    float s1 = __sinf(0.01227184630308512983f * (float)k1);
    float l1 = -4.0f * s1 * s1 * (RDX*RDX);
    float den = l1 + l2;
    float sc = ((k1 | k2) == 0) ? 0.0f : (1.0f/den);
    sc *= (1.0f/65536.0f);
    float2 v = Ab[g][k1];
    Ab[g][k1] = make_float2(v.x*sc, v.y*sc);
  }
  __syncthreads();
  fft256_dif_inv(Ab[g], lane);
  #pragma unroll
  for (int k = 0; k < 8; ++k) {
    int idx = tid + (k << 8);
    int i = idx >> 3, c = idx & 7;
    Sb[i*NN + col0 + c] = Ab[c][rev8(i)];
  }
}

__global__ __launch_bounds__(256) void fft_rows_inv(
    const float2* __restrict__ S, float* __restrict__ Q)
{
  __shared__ float2 Ab[TEAMS][NN];
  int tid = threadIdx.x;
  int b = blockIdx.x >> 5;
  int row0 = (blockIdx.x & 31) << 3;
  const float2* Sb = S + b*FIELD;
  #pragma unroll
  for (int k = 0; k < 8; ++k)
    Ab[k][tid] = Sb[(row0 + k)*NN + tid];
  __syncthreads();
  int g = tid >> 5, lane = tid & 31;
  fft256_dif_inv(Ab[g], lane);
  float* Qb = Q + b*FIELD;
  int rj = rev8(tid);
  #pragma unroll
  for (int k = 0; k < 8; ++k)
    Qb[(row0 + k)*NN + tid] = Ab[k][rj].x;
}

__global__ __launch_bounds__(256) void correct_uv(
    float* __restrict__ U2, float* __restrict__ V2, const float* __restrict__ Q)
{
  int idx = blockIdx.x*256 + threadIdx.x;
  int j = idx & NM;
  int i = (idx >> 8) & NM;
  int base = (idx >> 16) * FIELD;
  const float* Qb = Q + base;
  float q0 = Qb[i*NN + j];
  float qi = Qb[((i+1)&NM)*NN + j];
  float qj = Qb[i*NN + ((j+1)&NM)];
  U2[idx] -= (qi - q0)*RDX;
  V2[idx] -= (qj - q0)*RDX;
}

__global__ __launch_bounds__(256) void write_out_k(
    const float* __restrict__ U, const float* __restrict__ V, const float* __restrict__ D,
    float* __restrict__ out, int t, int T)
{
  int idx = blockIdx.x*256 + threadIdx.x;
  int b = idx >> 16;
  int pos = idx & (FIELD-1);
  size_t o = ((size_t)(b*T + t)*FIELD + pos)*3u;
  out[o]   = U[idx];
  out[o+1] = V[idx];
  out[o+2] = D[idx];
}

__global__ __launch_bounds__(256) void init_state(
    const float* __restrict__ y0,
    float* __restrict__ U, float* __restrict__ V, float* __restrict__ D)
{
  int idx = blockIdx.x*256 + threadIdx.x;
  U[idx] = y0[idx*3];
  V[idx] = y0[idx*3+1];
  D[idx] = y0[idx*3+2];
}

// ---------------------------------------------------------------- launch
extern "C" void kernel_launch(void* const* d_in, const int* in_sizes, int n_in,
                              void* d_out, int out_size, void* d_ws, size_t ws_size,
                              hipStream_t stream) {
  (void)in_sizes; (void)n_in; (void)ws_size;
  const float*    y0  = (const float*)d_in[0];
  const unsigned* dtw = (const unsigned*)d_in[1];
  float* out = (float*)d_out;

  int T = out_size / (3*FIELD*BATCH);
  if (T < 1) T = 1;

  float* wsf = (float*)d_ws;

  void* kargs[] = { (void*)&y0, (void*)&dtw, (void*)&out, (void*)&wsf, (void*)&T };
  hipError_t err = hipLaunchCooperativeKernel((const void*)ns_coop,
                                              dim3(512), dim3(256),
                                              kargs, 0, stream);
  if (err == hipSuccess) return;

  // ---------------- fallback: R5 multi-kernel path (aliased 12.6 MB ws)
  float* bank0 = wsf;
  float* bank1 = wsf + 3*TOTAL;
  init_state<<<TOTAL/256, 256, 0, stream>>>(y0, bank0, bank0+TOTAL, bank0+2*TOTAL);
  float* inb = bank0;
  float* outb = bank1;
  for (int t = 0; t < T; ++t) {
    for (int s = 0; s < 10; ++s) {
      float *Ui = inb,  *Vi = inb + TOTAL,  *Di = inb + 2*TOTAL;
      float *Uo = outb, *Vo = outb + TOTAL, *Do_ = outb + 2*TOTAL;
      float2* S = (float2*)(inb + TOTAL);   // aliases dead Vi,Di
      float*  Q = inb;                      // aliases dead Ui
      advect_kernel<<<TOTAL/256, 256, 0, stream>>>(Ui, Vi, Di, Uo, Vo, Do_, dtw);
      fft_rows_div <<<BATCH*32, 256, 0, stream>>>(Uo, Vo, S);
      fft_cols     <<<BATCH*32, 256, 0, stream>>>(S);
      fft_rows_inv <<<BATCH*32, 256, 0, stream>>>(S, Q);
      correct_uv   <<<TOTAL/256, 256, 0, stream>>>(Uo, Vo, Q);
      float* tmp = inb; inb = outb; outb = tmp;
    }
    write_out_k<<<TOTAL/256, 256, 0, stream>>>(inb, inb+TOTAL, inb+2*TOTAL, out, t, T);
  }
}

// Round 8
// 2870.321 us; speedup vs baseline: 7.3123x; 7.3123x over previous
//
#include <hip/hip_runtime.h>
#include <hip/hip_bf16.h>

// NS solver: 256x256 periodic, B=8, NC=3 (u,v,density), T outer x 10 inner steps.
// y0 = fp32, dt = fp32, out = fp32 (established R1-R5). Internal state fp32.
//
// R8: multi-kernel graph path, fused to the structural minimum of 3 kernels
// per inner step (R7 measured CG grid.sync at ~63 us/sync on MI355X -> the
// mega-kernel is a dead end; kernel boundaries are the cheap grid barrier).
//   K1 advect_div_fft : advect u,v,d (+1 redundant u-row for backward-diff
//                       div), div in LDS/regs, fwd row FFT -> S.
//                       write_out of previous state fused in (every 10th step).
//   K2 fft_cols       : fwd col FFT * invLam/N^2 * inv col FFT (in-place S)
//   K3 fft_inv_correct: inv row FFT (9 rows, 1 redundant) -> q in LDS,
//                       grad-q correction of u,v in place (R7-proven logic).
// 242 launches total (vs R5's 403). S has a dedicated region: ws = 8*TOTAL
// floats = 16.8 MB (guarded by ws_size; R5 5-kernel fallback otherwise).

#define NN 256
#define NM 255
#define FIELD (NN*NN)
#define BATCH 8
#define TOTAL (BATCH*FIELD)

constexpr float RDX  = 40.743665431525205f;   // N/(2*pi) = 1/DX
constexpr float VISC = 1e-3f;

__device__ __forceinline__ int rev8(int x) { return (int)(__brev((unsigned)x) >> 24); }

__device__ __forceinline__ float decode_dt(const unsigned* dtw) {
  unsigned w = dtw[0];
  float cf = __uint_as_float(w);
  float cb = __uint_as_float((w & 0xFFFFu) << 16);
  bool v32 = (cf > 1e-8f) && (cf < 1.0f);          // NaN-safe
  bool vbf = (cb > 1e-8f) && (cb < 1.0f);
  return v32 ? cf : (vbf ? cb : 1e-3f);
}

// ---------------------------------------------------------------- advection
__device__ __forceinline__ float face_flux(float uf, float cm, float c0,
                                           float cp, float cpp, float hdtdx) {
  float dc = cp - c0;
  float f_low  = (uf >= 0.0f) ? uf*c0 : uf*cp;
  float f_high = uf*0.5f*(c0+cp) - hdtdx*uf*uf*dc;
  float dc_up  = (uf >= 0.0f) ? (c0 - cm) : (cpp - cp);
  float dc_safe = (fabsf(dc) > 1e-12f) ? dc : 1e-12f;
  // van Leer: r=a/b, phi=(r>0)?2r/(1+r):0  ==  (a*b>0)?2a/(a+b):0
  float phi = (dc_up * dc_safe > 0.0f) ? (2.0f*dc_up/(dc_up + dc_safe)) : 0.0f;
  return f_low + phi*(f_high - f_low);
}

// Advect one point. NEED_VD=0: compute u1 only (redundant halo row for div).
template<int NEED_VD>
__device__ __forceinline__ void advect_point(
    const float* __restrict__ Ub, const float* __restrict__ Vb,
    const float* __restrict__ Db,
    int i, int j, float hdtdx, float dt,
    float& u1, float& v1, float& d1)
{
  int im2 = ((i-2)&NM)*NN, im1 = ((i-1)&NM)*NN, i0r = i*NN,
      ip1 = ((i+1)&NM)*NN, ip2 = ((i+2)&NM)*NN;
  int jm2 = (j-2)&NM, jm1 = (j-1)&NM, jp1 = (j+1)&NM, jp2 = (j+2)&NM;

  float u_c  = Ub[i0r+j];
  float u_im2= Ub[im2+j], u_im1 = Ub[im1+j], u_ip1 = Ub[ip1+j], u_ip2 = Ub[ip2+j];
  float u_jm2= Ub[i0r+jm2], u_jm1 = Ub[i0r+jm1], u_jp1 = Ub[i0r+jp1], u_jp2 = Ub[i0r+jp2];
  float v_c  = Vb[i0r+j];
  float v_jm1= Vb[i0r+jm1], v_jp1 = Vb[i0r+jp1];

  float ufI0 = 0.5f*(u_c + u_ip1);
  float ufIm = 0.5f*(u_im1 + u_c);
  float vfJ0 = 0.5f*(v_c + v_jp1);
  float vfJm = 0.5f*(v_jm1 + v_c);

  float tu = -(( face_flux(ufI0, u_im1, u_c, u_ip1, u_ip2, hdtdx)
               - face_flux(ufIm, u_im2, u_im1, u_c, u_ip1, hdtdx))
             + ( face_flux(vfJ0, u_jm1, u_c, u_jp1, u_jp2, hdtdx)
               - face_flux(vfJm, u_jm2, u_jm1, u_c, u_jp1, hdtdx))) * RDX;
  float lapu = (u_im1 + u_ip1 + u_jm1 + u_jp1 - 4.0f*u_c) * (RDX*RDX);
  u1 = u_c + dt*(tu + VISC*lapu);

  if (NEED_VD) {
    float v_im2= Vb[im2+j], v_im1 = Vb[im1+j], v_ip1 = Vb[ip1+j], v_ip2 = Vb[ip2+j];
    float v_jm2= Vb[i0r+jm2], v_jp2 = Vb[i0r+jp2];
    float d_c  = Db[i0r+j];
    float d_im2= Db[im2+j], d_im1 = Db[im1+j], d_ip1 = Db[ip1+j], d_ip2 = Db[ip2+j];
    float d_jm2= Db[i0r+jm2], d_jm1 = Db[i0r+jm1], d_jp1 = Db[i0r+jp1], d_jp2 = Db[i0r+jp2];

    float tv = -(( face_flux(ufI0, v_im1, v_c, v_ip1, v_ip2, hdtdx)
                 - face_flux(ufIm, v_im2, v_im1, v_c, v_ip1, hdtdx))
               + ( face_flux(vfJ0, v_jm1, v_c, v_jp1, v_jp2, hdtdx)
                 - face_flux(vfJm, v_jm2, v_jm1, v_c, v_jp1, hdtdx))) * RDX;
    float lapv = (v_im1 + v_ip1 + v_jm1 + v_jp1 - 4.0f*v_c) * (RDX*RDX);
    v1 = v_c + dt*(tv + VISC*lapv);

    float td = -(( face_flux(ufI0, d_im1, d_c, d_ip1, d_ip2, hdtdx)
                 - face_flux(ufIm, d_im2, d_im1, d_c, d_ip1, hdtdx))
               + ( face_flux(vfJ0, d_jm1, d_c, d_jp1, d_jp2, hdtdx)
                 - face_flux(vfJm, d_jm2, d_jm1, d_c, d_jp1, hdtdx))) * RDX;
    d1 = d_c + dt*td;
  }
}

// ---------------------------------------------------------------- FFT cores
// Forward: in-place radix-2 DIT; input pre-loaded BIT-REVERSED, natural out.
// `active=false` lanes skip work but hit every __syncthreads (wave-uniform).
__device__ __forceinline__ void fft256_dit_fwd(float2* __restrict__ A, int lane,
                                               bool active)
{
  #pragma unroll
  for (int s = 1; s <= 8; ++s) {
    int L = 1 << s, half = L >> 1;
    float angscale = -6.28318530717958647692f / (float)L;
    if (active) {
      #pragma unroll
      for (int r = 0; r < 4; ++r) {
        int bfly = lane + (r << 5);
        int q = bfly & (half - 1);
        int g = (bfly >> (s - 1)) << s;
        float sw, cw;
        __sincosf(angscale * (float)q, &sw, &cw);
        float2 a = A[g + q];
        float2 b = A[g + q + half];
        float wbx = cw*b.x - sw*b.y;
        float wby = cw*b.y + sw*b.x;
        A[g + q]        = make_float2(a.x + wbx, a.y + wby);
        A[g + q + half] = make_float2(a.x - wbx, a.y - wby);
      }
    }
    __syncthreads();
  }
}

// Inverse (unnormalized): in-place radix-2 DIF; natural in, BIT-REVERSED out.
__device__ __forceinline__ void fft256_dif_inv(float2* __restrict__ A, int lane,
                                               bool active)
{
  #pragma unroll
  for (int s = 8; s >= 1; --s) {
    int L = 1 << s, half = L >> 1;
    float angscale = 6.28318530717958647692f / (float)L;
    if (active) {
      #pragma unroll
      for (int r = 0; r < 4; ++r) {
        int bfly = lane + (r << 5);
        int q = bfly & (half - 1);
        int g = (bfly >> (s - 1)) << s;
        float sw, cw;
        __sincosf(angscale * (float)q, &sw, &cw);
        float2 a = A[g + q];
        float2 b = A[g + q + half];
        float dx = a.x - b.x, dy = a.y - b.y;
        A[g + q]        = make_float2(a.x + b.x, a.y + b.y);
        A[g + q + half] = make_float2(cw*dx - sw*dy, cw*dy + sw*dx);
      }
    }
    __syncthreads();
  }
}

// ================================================================ K1
// 256 blocks x 512 threads. Block = (batch b, 8-row group row0).
// half h = tid>>8 advects rows kbeg..kbeg+4 (kbeg = -1 or 3); the kk=0 row is
// u-only (redundant halo for div's backward diff). Then div -> bit-rev scatter
// -> fwd row FFT (first 256 threads) -> S. Optional write_out of inb fused.
__global__ __launch_bounds__(512) void advect_div_fft(
    const float* __restrict__ inb, float* __restrict__ outb,
    float2* __restrict__ S, float* __restrict__ out,
    const unsigned* __restrict__ dtw, int T, int tm1)
{
  __shared__ float  Vs[8][NN];        // advected v rows (for div's jm1)
  __shared__ float2 AbS[8*NN];        // FFT workspace
  const int tid = threadIdx.x;
  const int j   = tid & 255;
  const int h   = tid >> 8;           // 0 or 1
  const int b    = blockIdx.x >> 5;
  const int row0 = (blockIdx.x & 31) << 3;

  const float* Ub = inb + b*FIELD;
  const float* Vb = inb + TOTAL + b*FIELD;
  const float* Db = inb + 2*TOTAL + b*FIELD;
  float* Uo  = outb + b*FIELD;
  float* Vo  = outb + TOTAL + b*FIELD;
  float* Do_ = outb + 2*TOTAL + b*FIELD;

  const float dt = decode_dt(dtw);
  const float hdtdx = 0.5f*dt*RDX;

  // fused write_out of previous outer state (reads inb only)
  if (tm1 >= 0) {
    #pragma unroll
    for (int k = 0; k < 4; ++k) {
      int pos = (row0 + h*4 + k)*NN + j;
      size_t o = ((size_t)(b*T + tm1)*FIELD + pos)*3u;
      out[o]   = Ub[pos];
      out[o+1] = Vb[pos];
      out[o+2] = Db[pos];
    }
  }

  // advect 5 rows per half; kk=0 is u-only (redundant halo row)
  const int kbeg = h ? 3 : -1;
  float u1r[5];
  #pragma unroll
  for (int kk = 0; kk < 5; ++kk) {
    int k = kbeg + kk;
    int r = (row0 + k) & NM;
    float u1, v1, d1;
    if (kk == 0) {
      advect_point<0>(Ub, Vb, Db, r, j, hdtdx, dt, u1, v1, d1);
    } else {
      advect_point<1>(Ub, Vb, Db, r, j, hdtdx, dt, u1, v1, d1);
      int gi = r*NN + j;
      Uo[gi] = u1; Vo[gi] = v1; Do_[gi] = d1;
      Vs[k][j] = v1;
    }
    u1r[kk] = u1;
  }
  __syncthreads();

  // div (backward diff) -> bit-reversed scatter for DIT
  {
    int jm1 = (j - 1) & NM, rj = rev8(j);
    #pragma unroll
    for (int m = 0; m < 4; ++m) {
      int k = h*4 + m;
      float dv = (u1r[m+1] - u1r[m] + Vs[k][j] - Vs[k][jm1]) * RDX;
      AbS[(k<<8) + rj] = make_float2(dv, 0.0f);
    }
  }
  __syncthreads();

  // fwd row FFT on first 256 threads (8 teams x 32 lanes)
  const bool active = (tid < 256);
  const int g = (tid >> 5) & 7, lane = tid & 31;
  fft256_dit_fwd(AbS + (g<<8), lane, active);

  if (active) {
    float2* Sb = S + b*FIELD;
    #pragma unroll
    for (int k = 0; k < 8; ++k)
      Sb[(row0 + k)*NN + tid] = AbS[(k<<8) + tid];
  }
}

// ================================================================ K2
// fwd col FFT * invLam/N^2 * inv col FFT, in-place on S. (R5-proven.)
__global__ __launch_bounds__(256) void fft_cols(float2* __restrict__ S)
{
  __shared__ float2 Ab[8*NN];
  int tid = threadIdx.x;
  int b = blockIdx.x >> 5;
  int col0 = (blockIdx.x & 31) << 3;
  float2* Sb = S + b*FIELD;
  #pragma unroll
  for (int k = 0; k < 8; ++k) {
    int idx = tid + (k << 8);
    int i = idx >> 3, c = idx & 7;
    Ab[(c<<8) + rev8(i)] = Sb[i*NN + col0 + c];
  }
  __syncthreads();
  int g = tid >> 5, lane = tid & 31;
  fft256_dit_fwd(Ab + (g<<8), lane, true);
  int k2 = col0 + g;
  float s2 = __sinf(0.01227184630308512983f * (float)k2);   // pi/256*k
  float l2 = -4.0f * s2 * s2 * (RDX*RDX);
  #pragma unroll
  for (int r = 0; r < 8; ++r) {
    int k1 = lane + (r << 5);
    float s1 = __sinf(0.01227184630308512983f * (float)k1);
    float l1 = -4.0f * s1 * s1 * (RDX*RDX);
    float den = l1 + l2;
    float sc = ((k1 | k2) == 0) ? 0.0f : (1.0f/den);
    sc *= (1.0f/65536.0f);                 // fold in ifft2's 1/N^2
    float2 v = Ab[(g<<8) + k1];
    Ab[(g<<8) + k1] = make_float2(v.x*sc, v.y*sc);
  }
  __syncthreads();
  fft256_dif_inv(Ab + (g<<8), lane, true);
  #pragma unroll
  for (int k = 0; k < 8; ++k) {
    int idx = tid + (k << 8);
    int i = idx >> 3, c = idx & 7;
    Sb[i*NN + col0 + c] = Ab[(c<<8) + rev8(i)];
  }
}

// ================================================================ K3
// inv row FFT (rows row0..row0+8, one redundant) -> q in LDS; correct u,v.
// (R7-coop-P4-proven logic as a standalone kernel.)
__global__ __launch_bounds__(256) void fft_inv_correct(
    const float2* __restrict__ S, float* __restrict__ outb)
{
  __shared__ float  qs[9*NN];
  __shared__ float2 Ab[8*NN];
  int tid = threadIdx.x;
  int b = blockIdx.x >> 5;
  int row0 = (blockIdx.x & 31) << 3;
  int g = tid >> 5, lane = tid & 31, rj = rev8(tid);
  const float2* Sb = S + b*FIELD;
  #pragma unroll
  for (int k = 0; k < 8; ++k)
    Ab[(k<<8) + tid] = Sb[(row0 + k)*NN + tid];
  __syncthreads();
  fft256_dif_inv(Ab + (g<<8), lane, true);
  #pragma unroll
  for (int k = 0; k < 8; ++k)
    qs[(k<<8) + rj] = Ab[(k<<8) + tid].x;     // scatter un-reverse
  __syncthreads();
  int r8 = (row0 + 8) & NM;                   // 9th (redundant) row
  Ab[tid] = Sb[r8*NN + tid];
  __syncthreads();
  fft256_dif_inv(Ab + (g<<8), lane, true);    // teams 1..7 compute discard
  qs[(8<<8) + rj] = Ab[tid].x;
  __syncthreads();
  float* Ug = outb + b*FIELD;
  float* Vg = outb + TOTAL + b*FIELD;
  int jp1 = (tid + 1) & NM;
  #pragma unroll
  for (int k = 0; k < 8; ++k) {
    int gi = (row0 + k)*NN + tid;
    float q0 = qs[(k<<8) + tid];
    float q1 = qs[((k+1)<<8) + tid];
    float qj = qs[(k<<8) + jp1];
    Ug[gi] -= (q1 - q0)*RDX;
    Vg[gi] -= (qj - q0)*RDX;
  }
}

// ================================================================ misc
__global__ __launch_bounds__(256) void write_out_k(
    const float* __restrict__ U, const float* __restrict__ V, const float* __restrict__ D,
    float* __restrict__ out, int t, int T)
{
  int idx = blockIdx.x*256 + threadIdx.x;
  int b = idx >> 16;
  int pos = idx & (FIELD-1);
  size_t o = ((size_t)(b*T + t)*FIELD + pos)*3u;
  out[o]   = U[idx];
  out[o+1] = V[idx];
  out[o+2] = D[idx];
}

__global__ __launch_bounds__(256) void init_state(
    const float* __restrict__ y0,
    float* __restrict__ U, float* __restrict__ V, float* __restrict__ D)
{
  int idx = blockIdx.x*256 + threadIdx.x;
  U[idx] = y0[idx*3];
  V[idx] = y0[idx*3+1];
  D[idx] = y0[idx*3+2];
}

// ================================================================ fallback
// R5's proven 5-kernel path (used only if ws_size < 8*TOTAL floats).
__global__ __launch_bounds__(256) void advect_kernel(
    const float* __restrict__ U, const float* __restrict__ V, const float* __restrict__ D,
    float* __restrict__ Uo, float* __restrict__ Vo, float* __restrict__ Do_,
    const unsigned* __restrict__ dtw)
{
  int idx = blockIdx.x*256 + threadIdx.x;
  int j = idx & NM;
  int i = (idx >> 8) & NM;
  int base = (idx >> 16) * FIELD;
  float dt = decode_dt(dtw);
  float u1, v1, d1;
  advect_point<1>(U + base, V + base, D + base, i, j, 0.5f*dt*RDX, dt, u1, v1, d1);
  Uo[idx] = u1; Vo[idx] = v1; Do_[idx] = d1;
}

__global__ __launch_bounds__(256) void fft_rows_div_fb(
    const float* __restrict__ U2, const float* __restrict__ V2, float2* __restrict__ S)
{
  __shared__ float2 Ab[8*NN];
  int tid = threadIdx.x;
  int b = blockIdx.x >> 5;
  int row0 = (blockIdx.x & 31) << 3;
  const float* Ub = U2 + b*FIELD;
  const float* Vb = V2 + b*FIELD;
  int jm1 = (tid - 1) & NM;
  int rj = rev8(tid);
  #pragma unroll
  for (int k = 0; k < 8; ++k) {
    int row = row0 + k, rm1 = (row - 1) & NM;
    float dv = (Ub[row*NN + tid] - Ub[rm1*NN + tid]
              + Vb[row*NN + tid] - Vb[row*NN + jm1]) * RDX;
    Ab[(k<<8) + rj] = make_float2(dv, 0.0f);
  }
  __syncthreads();
  int g = tid >> 5, lane = tid & 31;
  fft256_dit_fwd(Ab + (g<<8), lane, true);
  float2* Sb = S + b*FIELD;
  #pragma unroll
  for (int k = 0; k < 8; ++k)
    Sb[(row0 + k)*NN + tid] = Ab[(k<<8) + tid];
}

__global__ __launch_bounds__(256) void fft_rows_inv_fb(
    const float2* __restrict__ S, float* __restrict__ Q)
{
  __shared__ float2 Ab[8*NN];
  int tid = threadIdx.x;
  int b = blockIdx.x >> 5;
  int row0 = (blockIdx.x & 31) << 3;
  const float2* Sb = S + b*FIELD;
  #pragma unroll
  for (int k = 0; k < 8; ++k)
    Ab[(k<<8) + tid] = Sb[(row0 + k)*NN + tid];
  __syncthreads();
  int g = tid >> 5, lane = tid & 31;
  fft256_dif_inv(Ab + (g<<8), lane, true);
  float* Qb = Q + b*FIELD;
  int rj = rev8(tid);
  #pragma unroll
  for (int k = 0; k < 8; ++k)
    Qb[(row0 + k)*NN + tid] = Ab[(k<<8) + rj].x;
}

__global__ __launch_bounds__(256) void correct_uv_fb(
    float* __restrict__ U2, float* __restrict__ V2, const float* __restrict__ Q)
{
  int idx = blockIdx.x*256 + threadIdx.x;
  int j = idx & NM;
  int i = (idx >> 8) & NM;
  int base = (idx >> 16) * FIELD;
  const float* Qb = Q + base;
  float q0 = Qb[i*NN + j];
  float qi = Qb[((i+1)&NM)*NN + j];
  float qj = Qb[i*NN + ((j+1)&NM)];
  U2[idx] -= (qi - q0)*RDX;
  V2[idx] -= (qj - q0)*RDX;
}

// ---------------------------------------------------------------- launch
extern "C" void kernel_launch(void* const* d_in, const int* in_sizes, int n_in,
                              void* d_out, int out_size, void* d_ws, size_t ws_size,
                              hipStream_t stream) {
  (void)in_sizes; (void)n_in;
  const float*    y0  = (const float*)d_in[0];
  const unsigned* dtw = (const unsigned*)d_in[1];
  float* out = (float*)d_out;

  int T = out_size / (3*FIELD*BATCH);
  if (T < 1) T = 1;

  float* wsf = (float*)d_ws;

  if (ws_size >= (size_t)8*TOTAL*sizeof(float)) {
    // main path: bank0 | bank1 | S(dedicated 2*TOTAL floats)
    float2* S = (float2*)(wsf + 6*TOTAL);
    init_state<<<TOTAL/256, 256, 0, stream>>>(y0, wsf, wsf+TOTAL, wsf+2*TOTAL);
    float* inb = wsf;
    float* outb = wsf + 3*TOTAL;
    for (int t = 0; t < T; ++t) {
      for (int s = 0; s < 10; ++s) {
        int tm1 = (s == 0) ? (t - 1) : -1;   // -1: no fused write_out
        advect_div_fft <<<256, 512, 0, stream>>>(inb, outb, S, out, dtw, T, tm1);
        fft_cols       <<<256, 256, 0, stream>>>(S);
        fft_inv_correct<<<256, 256, 0, stream>>>(S, outb);
        float* tmp = inb; inb = outb; outb = tmp;
      }
    }
    write_out_k<<<TOTAL/256, 256, 0, stream>>>(inb, inb+TOTAL, inb+2*TOTAL,
                                               out, T-1, T);
    return;
  }

  // fallback: R5 5-kernel path with aliased S/Q (12.6 MB)
  float* bank0 = wsf;
  float* bank1 = wsf + 3*TOTAL;
  init_state<<<TOTAL/256, 256, 0, stream>>>(y0, bank0, bank0+TOTAL, bank0+2*TOTAL);
  float* inb = bank0;
  float* outb = bank1;
  for (int t = 0; t < T; ++t) {
    for (int s = 0; s < 10; ++s) {
      float *Ui = inb,  *Vi = inb + TOTAL,  *Di = inb + 2*TOTAL;
      float *Uo = outb, *Vo = outb + TOTAL, *Do_ = outb + 2*TOTAL;
      float2* S = (float2*)(inb + TOTAL);   // aliases dead Vi,Di
      float*  Q = inb;                      // aliases dead Ui
      advect_kernel  <<<TOTAL/256, 256, 0, stream>>>(Ui, Vi, Di, Uo, Vo, Do_, dtw);
      fft_rows_div_fb<<<BATCH*32, 256, 0, stream>>>(Uo, Vo, S);
      fft_cols       <<<BATCH*32, 256, 0, stream>>>(S);
      fft_rows_inv_fb<<<BATCH*32, 256, 0, stream>>>(S, Q);
      correct_uv_fb  <<<TOTAL/256, 256, 0, stream>>>(Uo, Vo, Q);
      float* tmp = inb; inb = outb; outb = tmp;
    }
    write_out_k<<<TOTAL/256, 256, 0, stream>>>(inb, inb+TOTAL, inb+2*TOTAL, out, t, T);
  }
}

// Round 9
// 2559.930 us; speedup vs baseline: 8.1989x; 1.1213x over previous
//
#include <hip/hip_runtime.h>
#include <hip/hip_bf16.h>

// NS solver: 256x256 periodic, B=8, NC=3 (u,v,density), T outer x 10 inner steps.
// y0 = fp32, dt = fp32, out = fp32 (established R1-R5). Internal state fp32.
//
// R9: same 3-kernel/step skeleton as R8 (242 launches), FFT internals rebuilt:
//  - LDS twiddle table (tw[m]=e^{-2pi i m/256}); stage twiddle = tw[q<<(8-s)],
//    conj for inverse. No per-butterfly __sincosf (quarter-rate pipe).
//  - padded LDS indexing pdx(x)=x+(x>>5), row stride 264 float2: fixes the
//    16-way bit-rev scatter conflicts + 8-way stride-2 DIT stages (R7 PMC:
//    SQ_LDS_BANK_CONFLICT=2.1e8 on these patterns).
//  - K1/K2: 512 threads, 8 teams x 64 lanes (half the butterfly depth).
//  - K3: 512 threads, 9 row-FFTs in ONE pass (9 of 16 32-lane teams) instead
//    of 8 + a second nearly-idle pass.
// ws = 8*TOTAL floats = 16.8 MB; R5-style fallback if ws too small.

#define NN 256
#define NM 255
#define FIELD (NN*NN)
#define BATCH 8
#define TOTAL (BATCH*FIELD)
#define ROWF2 264   // padded LDS row stride in float2 (256 + 8)

constexpr float RDX  = 40.743665431525205f;   // N/(2*pi) = 1/DX
constexpr float VISC = 1e-3f;

__device__ __forceinline__ int rev8(int x) { return (int)(__brev((unsigned)x) >> 24); }
__device__ __forceinline__ int pdx(int x)  { return x + (x >> 5); }

__device__ __forceinline__ float decode_dt(const unsigned* dtw) {
  unsigned w = dtw[0];
  float cf = __uint_as_float(w);
  float cb = __uint_as_float((w & 0xFFFFu) << 16);
  bool v32 = (cf > 1e-8f) && (cf < 1.0f);          // NaN-safe
  bool vbf = (cb > 1e-8f) && (cb < 1.0f);
  return v32 ? cf : (vbf ? cb : 1e-3f);
}

// ---------------------------------------------------------------- advection
__device__ __forceinline__ float face_flux(float uf, float cm, float c0,
                                           float cp, float cpp, float hdtdx) {
  float dc = cp - c0;
  float f_low  = (uf >= 0.0f) ? uf*c0 : uf*cp;
  float f_high = uf*0.5f*(c0+cp) - hdtdx*uf*uf*dc;
  float dc_up  = (uf >= 0.0f) ? (c0 - cm) : (cpp - cp);
  float dc_safe = (fabsf(dc) > 1e-12f) ? dc : 1e-12f;
  // van Leer: (a*b>0) ? 2a/(a+b) : 0
  float phi = (dc_up * dc_safe > 0.0f) ? (2.0f*dc_up/(dc_up + dc_safe)) : 0.0f;
  return f_low + phi*(f_high - f_low);
}

template<int NEED_VD>
__device__ __forceinline__ void advect_point(
    const float* __restrict__ Ub, const float* __restrict__ Vb,
    const float* __restrict__ Db,
    int i, int j, float hdtdx, float dt,
    float& u1, float& v1, float& d1)
{
  int im2 = ((i-2)&NM)*NN, im1 = ((i-1)&NM)*NN, i0r = i*NN,
      ip1 = ((i+1)&NM)*NN, ip2 = ((i+2)&NM)*NN;
  int jm2 = (j-2)&NM, jm1 = (j-1)&NM, jp1 = (j+1)&NM, jp2 = (j+2)&NM;

  float u_c  = Ub[i0r+j];
  float u_im2= Ub[im2+j], u_im1 = Ub[im1+j], u_ip1 = Ub[ip1+j], u_ip2 = Ub[ip2+j];
  float u_jm2= Ub[i0r+jm2], u_jm1 = Ub[i0r+jm1], u_jp1 = Ub[i0r+jp1], u_jp2 = Ub[i0r+jp2];
  float v_c  = Vb[i0r+j];
  float v_jm1= Vb[i0r+jm1], v_jp1 = Vb[i0r+jp1];

  float ufI0 = 0.5f*(u_c + u_ip1);
  float ufIm = 0.5f*(u_im1 + u_c);
  float vfJ0 = 0.5f*(v_c + v_jp1);
  float vfJm = 0.5f*(v_jm1 + v_c);

  float tu = -(( face_flux(ufI0, u_im1, u_c, u_ip1, u_ip2, hdtdx)
               - face_flux(ufIm, u_im2, u_im1, u_c, u_ip1, hdtdx))
             + ( face_flux(vfJ0, u_jm1, u_c, u_jp1, u_jp2, hdtdx)
               - face_flux(vfJm, u_jm2, u_jm1, u_c, u_jp1, hdtdx))) * RDX;
  float lapu = (u_im1 + u_ip1 + u_jm1 + u_jp1 - 4.0f*u_c) * (RDX*RDX);
  u1 = u_c + dt*(tu + VISC*lapu);

  if (NEED_VD) {
    float v_im2= Vb[im2+j], v_im1 = Vb[im1+j], v_ip1 = Vb[ip1+j], v_ip2 = Vb[ip2+j];
    float v_jm2= Vb[i0r+jm2], v_jp2 = Vb[i0r+jp2];
    float d_c  = Db[i0r+j];
    float d_im2= Db[im2+j], d_im1 = Db[im1+j], d_ip1 = Db[ip1+j], d_ip2 = Db[ip2+j];
    float d_jm2= Db[i0r+jm2], d_jm1 = Db[i0r+jm1], d_jp1 = Db[i0r+jp1], d_jp2 = Db[i0r+jp2];

    float tv = -(( face_flux(ufI0, v_im1, v_c, v_ip1, v_ip2, hdtdx)
                 - face_flux(ufIm, v_im2, v_im1, v_c, v_ip1, hdtdx))
               + ( face_flux(vfJ0, v_jm1, v_c, v_jp1, v_jp2, hdtdx)
                 - face_flux(vfJm, v_jm2, v_jm1, v_c, v_jp1, hdtdx))) * RDX;
    float lapv = (v_im1 + v_ip1 + v_jm1 + v_jp1 - 4.0f*v_c) * (RDX*RDX);
    v1 = v_c + dt*(tv + VISC*lapv);

    float td = -(( face_flux(ufI0, d_im1, d_c, d_ip1, d_ip2, hdtdx)
                 - face_flux(ufIm, d_im2, d_im1, d_c, d_ip1, hdtdx))
               + ( face_flux(vfJ0, d_jm1, d_c, d_jp1, d_jp2, hdtdx)
                 - face_flux(vfJm, d_jm2, d_jm1, d_c, d_jp1, hdtdx))) * RDX;
    d1 = d_c + dt*td;
  }
}

// ---------------------------------------------------------------- FFT cores
// Table-driven, padded-LDS, W lanes per 256-pt FFT (W=32 or 64).
// tw[m] = exp(-2*pi*i*m/256), m<128. Stage-s twiddle = tw[q<<(8-s)] (fwd),
// conjugate for inverse. A = padded row base; element x lives at A[pdx(x)].
template<int W>
__device__ __forceinline__ void fft256_dit_fwd(float2* __restrict__ A, int lane,
                                               const float2* __restrict__ tw,
                                               bool active)
{
  #pragma unroll
  for (int s = 1; s <= 8; ++s) {
    int half = 1 << (s-1);
    if (active) {
      #pragma unroll
      for (int r = 0; r < 128/W; ++r) {
        int bfly = lane + r*W;
        int q = bfly & (half - 1);
        int g = (bfly >> (s-1)) << s;
        float2 w = tw[q << (8 - s)];
        float2 a = A[pdx(g + q)];
        float2 b = A[pdx(g + q + half)];
        float wbx = w.x*b.x - w.y*b.y;
        float wby = w.x*b.y + w.y*b.x;
        A[pdx(g + q)]        = make_float2(a.x + wbx, a.y + wby);
        A[pdx(g + q + half)] = make_float2(a.x - wbx, a.y - wby);
      }
    }
    __syncthreads();
  }
}

template<int W>
__device__ __forceinline__ void fft256_dif_inv(float2* __restrict__ A, int lane,
                                               const float2* __restrict__ tw,
                                               bool active)
{
  #pragma unroll
  for (int s = 8; s >= 1; --s) {
    int half = 1 << (s-1);
    if (active) {
      #pragma unroll
      for (int r = 0; r < 128/W; ++r) {
        int bfly = lane + r*W;
        int q = bfly & (half - 1);
        int g = (bfly >> (s-1)) << s;
        float2 w = tw[q << (8 - s)];      // conj applied below (inverse)
        float2 a = A[pdx(g + q)];
        float2 b = A[pdx(g + q + half)];
        float dx = a.x - b.x, dy = a.y - b.y;
        A[pdx(g + q)]        = make_float2(a.x + b.x, a.y + b.y);
        A[pdx(g + q + half)] = make_float2(w.x*dx + w.y*dy, w.x*dy - w.y*dx);
      }
    }
    __syncthreads();
  }
}

// ================================================================ K1
// 256 blocks x 512 threads. Advect (2 halves x 5 rows, 1 redundant u-halo),
// div -> bit-rev scatter (padded), fwd row FFT (8 teams x 64 lanes) -> S.
__global__ __launch_bounds__(512) void advect_div_fft(
    const float* __restrict__ inb, float* __restrict__ outb,
    float2* __restrict__ S, float* __restrict__ out,
    const unsigned* __restrict__ dtw, int T, int tm1)
{
  __shared__ float  Vs[8][NN];
  __shared__ float2 AbS[8*ROWF2];
  __shared__ float2 tw[128];
  const int tid = threadIdx.x;
  const int j   = tid & 255;
  const int h   = tid >> 8;           // 0 or 1
  const int b    = blockIdx.x >> 5;
  const int row0 = (blockIdx.x & 31) << 3;

  if (tid < 128) {
    float sw, cw;
    __sincosf(-0.02454369260617026f * (float)tid, &sw, &cw);  // -2pi/256
    tw[tid] = make_float2(cw, sw);
  }

  const float* Ub = inb + b*FIELD;
  const float* Vb = inb + TOTAL + b*FIELD;
  const float* Db = inb + 2*TOTAL + b*FIELD;
  float* Uo  = outb + b*FIELD;
  float* Vo  = outb + TOTAL + b*FIELD;
  float* Do_ = outb + 2*TOTAL + b*FIELD;

  const float dt = decode_dt(dtw);
  const float hdtdx = 0.5f*dt*RDX;

  if (tm1 >= 0) {                      // fused write_out of previous state
    #pragma unroll
    for (int k = 0; k < 4; ++k) {
      int pos = (row0 + h*4 + k)*NN + j;
      size_t o = ((size_t)(b*T + tm1)*FIELD + pos)*3u;
      out[o]   = Ub[pos];
      out[o+1] = Vb[pos];
      out[o+2] = Db[pos];
    }
  }

  const int kbeg = h ? 3 : -1;
  float u1r[5];
  #pragma unroll
  for (int kk = 0; kk < 5; ++kk) {
    int k = kbeg + kk;
    int r = (row0 + k) & NM;
    float u1, v1, d1;
    if (kk == 0) {
      advect_point<0>(Ub, Vb, Db, r, j, hdtdx, dt, u1, v1, d1);
    } else {
      advect_point<1>(Ub, Vb, Db, r, j, hdtdx, dt, u1, v1, d1);
      int gi = r*NN + j;
      Uo[gi] = u1; Vo[gi] = v1; Do_[gi] = d1;
      Vs[k][j] = v1;
    }
    u1r[kk] = u1;
  }
  __syncthreads();

  {  // div (backward diff) -> bit-reversed scatter (padded)
    int jm1 = (j - 1) & NM, rj = rev8(j);
    #pragma unroll
    for (int m = 0; m < 4; ++m) {
      int k = h*4 + m;
      float dv = (u1r[m+1] - u1r[m] + Vs[k][j] - Vs[k][jm1]) * RDX;
      AbS[k*ROWF2 + pdx(rj)] = make_float2(dv, 0.0f);
    }
  }
  __syncthreads();

  // fwd row FFT: 8 teams x 64 lanes
  const int g = tid >> 6, lane = tid & 63;
  fft256_dit_fwd<64>(AbS + g*ROWF2, lane, tw, true);

  float2* Sb = S + b*FIELD;
  #pragma unroll
  for (int k = 0; k < 4; ++k) {
    int row = h*4 + k;
    Sb[(row0 + row)*NN + j] = AbS[row*ROWF2 + pdx(j)];
  }
}

// ================================================================ K2
// 256 blocks x 512 threads. fwd col FFT * invLam/N^2 * inv col FFT, in place.
__global__ __launch_bounds__(512) void fft_cols(float2* __restrict__ S)
{
  __shared__ float2 Ab[8*ROWF2];
  __shared__ float2 tw[128];
  __shared__ float  lam[NN];
  int tid = threadIdx.x;
  int b = blockIdx.x >> 5;
  int col0 = (blockIdx.x & 31) << 3;

  if (tid < 128) {
    float sw, cw;
    __sincosf(-0.02454369260617026f * (float)tid, &sw, &cw);
    tw[tid] = make_float2(cw, sw);
  }
  if (tid < 256) {
    float s1 = __sinf(0.01227184630308512983f * (float)tid);   // pi/256 * k
    lam[tid] = -4.0f * s1 * s1 * (RDX*RDX);
  }

  float2* Sb = S + b*FIELD;
  #pragma unroll
  for (int k = 0; k < 4; ++k) {        // load transposed, bit-reversed
    int idx = tid + (k << 9);
    int i = idx >> 3, c = idx & 7;
    Ab[c*ROWF2 + pdx(rev8(i))] = Sb[i*NN + col0 + c];
  }
  __syncthreads();

  int g = tid >> 6, lane = tid & 63;
  fft256_dit_fwd<64>(Ab + g*ROWF2, lane, tw, true);

  float l2 = lam[col0 + g];
  #pragma unroll
  for (int r = 0; r < 4; ++r) {
    int k1 = lane + (r << 6);
    float den = lam[k1] + l2;
    float sc = ((k1 | (col0 + g)) == 0) ? 0.0f : (1.0f/den);
    sc *= (1.0f/65536.0f);             // fold in ifft2's 1/N^2
    float2 v = Ab[g*ROWF2 + pdx(k1)];
    Ab[g*ROWF2 + pdx(k1)] = make_float2(v.x*sc, v.y*sc);
  }
  __syncthreads();

  fft256_dif_inv<64>(Ab + g*ROWF2, lane, tw, true);

  #pragma unroll
  for (int k = 0; k < 4; ++k) {        // store transposed, un-reversed
    int idx = tid + (k << 9);
    int i = idx >> 3, c = idx & 7;
    Sb[i*NN + col0 + c] = Ab[c*ROWF2 + pdx(rev8(i))];
  }
}

// ================================================================ K3
// 256 blocks x 512 threads. Inv row FFT of 9 rows (1 redundant) in ONE pass
// (teams 0..8 of 32 lanes), q in LDS, grad-q correction of u,v in place.
__global__ __launch_bounds__(512) void fft_inv_correct(
    const float2* __restrict__ S, float* __restrict__ outb)
{
  __shared__ float2 Ab[9*ROWF2];
  __shared__ float  qs[9*NN];
  __shared__ float2 tw[128];
  int tid = threadIdx.x;
  int b = blockIdx.x >> 5;
  int row0 = (blockIdx.x & 31) << 3;

  if (tid < 128) {
    float sw, cw;
    __sincosf(-0.02454369260617026f * (float)tid, &sw, &cw);
    tw[tid] = make_float2(cw, sw);
  }

  const float2* Sb = S + b*FIELD;
  #pragma unroll
  for (int m = 0; m < 5; ++m) {        // load 9 rows, natural order (DIF in)
    int e = tid + m*512;
    if (e < 9*NN) {
      int k = e >> 8, j = e & 255;
      Ab[k*ROWF2 + pdx(j)] = Sb[((row0 + k) & NM)*NN + j];
    }
  }
  __syncthreads();

  int g = tid >> 5, lane = tid & 31;   // 16 teams of 32; 9 active
  bool active = (g < 9);
  fft256_dif_inv<32>(Ab + (active ? g : 8)*ROWF2, lane, tw, active);

  #pragma unroll
  for (int m = 0; m < 5; ++m) {        // un-reverse gather -> qs natural
    int e = tid + m*512;
    if (e < 9*NN) {
      int k = e >> 8, j = e & 255;
      qs[k*NN + j] = Ab[k*ROWF2 + pdx(rev8(j))].x;
    }
  }
  __syncthreads();

  float* Ug = outb + b*FIELD;
  float* Vg = outb + TOTAL + b*FIELD;
  #pragma unroll
  for (int m = 0; m < 4; ++m) {
    int e = tid + m*512;               // 0..2047
    int k = e >> 8, j = e & 255;
    int gi = (row0 + k)*NN + j;
    float q0 = qs[k*NN + j];
    float q1 = qs[(k+1)*NN + j];
    float qj = qs[k*NN + ((j+1) & NM)];
    Ug[gi] -= (q1 - q0)*RDX;
    Vg[gi] -= (qj - q0)*RDX;
  }
}

// ================================================================ misc
__global__ __launch_bounds__(256) void write_out_k(
    const float* __restrict__ U, const float* __restrict__ V, const float* __restrict__ D,
    float* __restrict__ out, int t, int T)
{
  int idx = blockIdx.x*256 + threadIdx.x;
  int b = idx >> 16;
  int pos = idx & (FIELD-1);
  size_t o = ((size_t)(b*T + t)*FIELD + pos)*3u;
  out[o]   = U[idx];
  out[o+1] = V[idx];
  out[o+2] = D[idx];
}

__global__ __launch_bounds__(256) void init_state(
    const float* __restrict__ y0,
    float* __restrict__ U, float* __restrict__ V, float* __restrict__ D)
{
  int idx = blockIdx.x*256 + threadIdx.x;
  U[idx] = y0[idx*3];
  V[idx] = y0[idx*3+1];
  D[idx] = y0[idx*3+2];
}

// ================================================================ fallback
// R5-proven sincos/unpadded kernels (used only if ws too small).
__device__ __forceinline__ void fft_fwd_sc(float2* A, int lane) {
  #pragma unroll
  for (int s = 1; s <= 8; ++s) {
    int half = 1 << (s-1);
    float angscale = -6.28318530717958647692f / (float)(2*half);
    #pragma unroll
    for (int r = 0; r < 4; ++r) {
      int bfly = lane + (r << 5);
      int q = bfly & (half - 1);
      int g = (bfly >> (s-1)) << s;
      float sw, cw; __sincosf(angscale * (float)q, &sw, &cw);
      float2 a = A[g+q], b = A[g+q+half];
      float wbx = cw*b.x - sw*b.y, wby = cw*b.y + sw*b.x;
      A[g+q] = make_float2(a.x+wbx, a.y+wby);
      A[g+q+half] = make_float2(a.x-wbx, a.y-wby);
    }
    __syncthreads();
  }
}
__device__ __forceinline__ void fft_inv_sc(float2* A, int lane) {
  #pragma unroll
  for (int s = 8; s >= 1; --s) {
    int half = 1 << (s-1);
    float angscale = 6.28318530717958647692f / (float)(2*half);
    #pragma unroll
    for (int r = 0; r < 4; ++r) {
      int bfly = lane + (r << 5);
      int q = bfly & (half - 1);
      int g = (bfly >> (s-1)) << s;
      float sw, cw; __sincosf(angscale * (float)q, &sw, &cw);
      float2 a = A[g+q], b = A[g+q+half];
      float dx = a.x-b.x, dy = a.y-b.y;
      A[g+q] = make_float2(a.x+b.x, a.y+b.y);
      A[g+q+half] = make_float2(cw*dx - sw*dy, cw*dy + sw*dx);
    }
    __syncthreads();
  }
}

__global__ __launch_bounds__(256) void advect_kernel_fb(
    const float* __restrict__ U, const float* __restrict__ V, const float* __restrict__ D,
    float* __restrict__ Uo, float* __restrict__ Vo, float* __restrict__ Do_,
    const unsigned* __restrict__ dtw)
{
  int idx = blockIdx.x*256 + threadIdx.x;
  int j = idx & NM, i = (idx >> 8) & NM, base = (idx >> 16) * FIELD;
  float dt = decode_dt(dtw);
  float u1, v1, d1;
  advect_point<1>(U + base, V + base, D + base, i, j, 0.5f*dt*RDX, dt, u1, v1, d1);
  Uo[idx] = u1; Vo[idx] = v1; Do_[idx] = d1;
}

__global__ __launch_bounds__(256) void fft_rows_div_fb(
    const float* __restrict__ U2, const float* __restrict__ V2, float2* __restrict__ S)
{
  __shared__ float2 Ab[8*NN];
  int tid = threadIdx.x, b = blockIdx.x >> 5, row0 = (blockIdx.x & 31) << 3;
  const float* Ub = U2 + b*FIELD;
  const float* Vb = V2 + b*FIELD;
  int jm1 = (tid - 1) & NM, rj = rev8(tid);
  #pragma unroll
  for (int k = 0; k < 8; ++k) {
    int row = row0 + k, rm1 = (row - 1) & NM;
    float dv = (Ub[row*NN + tid] - Ub[rm1*NN + tid]
              + Vb[row*NN + tid] - Vb[row*NN + jm1]) * RDX;
    Ab[(k<<8) + rj] = make_float2(dv, 0.0f);
  }
  __syncthreads();
  int g = tid >> 5, lane = tid & 31;
  fft_fwd_sc(Ab + (g<<8), lane);
  float2* Sb = S + b*FIELD;
  #pragma unroll
  for (int k = 0; k < 8; ++k)
    Sb[(row0 + k)*NN + tid] = Ab[(k<<8) + tid];
}

__global__ __launch_bounds__(256) void fft_cols_fb(float2* __restrict__ S)
{
  __shared__ float2 Ab[8*NN];
  int tid = threadIdx.x, b = blockIdx.x >> 5, col0 = (blockIdx.x & 31) << 3;
  float2* Sb = S + b*FIELD;
  #pragma unroll
  for (int k = 0; k < 8; ++k) {
    int idx = tid + (k << 8);
    int i = idx >> 3, c = idx & 7;
    Ab[(c<<8) + rev8(i)] = Sb[i*NN + col0 + c];
  }
  __syncthreads();
  int g = tid >> 5, lane = tid & 31;
  fft_fwd_sc(Ab + (g<<8), lane);
  int k2 = col0 + g;
  float s2 = __sinf(0.01227184630308512983f * (float)k2);
  float l2 = -4.0f * s2 * s2 * (RDX*RDX);
  #pragma unroll
  for (int r = 0; r < 8; ++r) {
    int k1 = lane + (r << 5);
    float s1 = __sinf(0.01227184630308512983f * (float)k1);
    float l1 = -4.0f * s1 * s1 * (RDX*RDX);
    float den = l1 + l2;
    float sc = ((k1 | k2) == 0) ? 0.0f : (1.0f/den);
    sc *= (1.0f/65536.0f);
    float2 v = Ab[(g<<8) + k1];
    Ab[(g<<8) + k1] = make_float2(v.x*sc, v.y*sc);
  }
  __syncthreads();
  fft_inv_sc(Ab + (g<<8), lane);
  #pragma unroll
  for (int k = 0; k < 8; ++k) {
    int idx = tid + (k << 8);
    int i = idx >> 3, c = idx & 7;
    Sb[i*NN + col0 + c] = Ab[(c<<8) + rev8(i)];
  }
}

__global__ __launch_bounds__(256) void fft_rows_inv_fb(
    const float2* __restrict__ S, float* __restrict__ Q)
{
  __shared__ float2 Ab[8*NN];
  int tid = threadIdx.x, b = blockIdx.x >> 5, row0 = (blockIdx.x & 31) << 3;
  const float2* Sb = S + b*FIELD;
  #pragma unroll
  for (int k = 0; k < 8; ++k)
    Ab[(k<<8) + tid] = Sb[(row0 + k)*NN + tid];
  __syncthreads();
  int g = tid >> 5, lane = tid & 31;
  fft_inv_sc(Ab + (g<<8), lane);
  float* Qb = Q + b*FIELD;
  int rj = rev8(tid);
  #pragma unroll
  for (int k = 0; k < 8; ++k)
    Qb[(row0 + k)*NN + tid] = Ab[(k<<8) + rj].x;
}

__global__ __launch_bounds__(256) void correct_uv_fb(
    float* __restrict__ U2, float* __restrict__ V2, const float* __restrict__ Q)
{
  int idx = blockIdx.x*256 + threadIdx.x;
  int j = idx & NM, i = (idx >> 8) & NM, base = (idx >> 16) * FIELD;
  const float* Qb = Q + base;
  float q0 = Qb[i*NN + j];
  float qi = Qb[((i+1)&NM)*NN + j];
  float qj = Qb[i*NN + ((j+1)&NM)];
  U2[idx] -= (qi - q0)*RDX;
  V2[idx] -= (qj - q0)*RDX;
}

// ---------------------------------------------------------------- launch
extern "C" void kernel_launch(void* const* d_in, const int* in_sizes, int n_in,
                              void* d_out, int out_size, void* d_ws, size_t ws_size,
                              hipStream_t stream) {
  (void)in_sizes; (void)n_in;
  const float*    y0  = (const float*)d_in[0];
  const unsigned* dtw = (const unsigned*)d_in[1];
  float* out = (float*)d_out;

  int T = out_size / (3*FIELD*BATCH);
  if (T < 1) T = 1;

  float* wsf = (float*)d_ws;

  if (ws_size >= (size_t)8*TOTAL*sizeof(float)) {
    float2* S = (float2*)(wsf + 6*TOTAL);
    init_state<<<TOTAL/256, 256, 0, stream>>>(y0, wsf, wsf+TOTAL, wsf+2*TOTAL);
    float* inb = wsf;
    float* outb = wsf + 3*TOTAL;
    for (int t = 0; t < T; ++t) {
      for (int s = 0; s < 10; ++s) {
        int tm1 = (s == 0) ? (t - 1) : -1;
        advect_div_fft <<<256, 512, 0, stream>>>(inb, outb, S, out, dtw, T, tm1);
        fft_cols       <<<256, 512, 0, stream>>>(S);
        fft_inv_correct<<<256, 512, 0, stream>>>(S, outb);
        float* tmp = inb; inb = outb; outb = tmp;
      }
    }
    write_out_k<<<TOTAL/256, 256, 0, stream>>>(inb, inb+TOTAL, inb+2*TOTAL,
                                               out, T-1, T);
    return;
  }

  // fallback: R5 5-kernel path with aliased S/Q (12.6 MB)
  float* bank0 = wsf;
  float* bank1 = wsf + 3*TOTAL;
  init_state<<<TOTAL/256, 256, 0, stream>>>(y0, bank0, bank0+TOTAL, bank0+2*TOTAL);
  float* inb = bank0;
  float* outb = bank1;
  for (int t = 0; t < T; ++t) {
    for (int s = 0; s < 10; ++s) {
      float *Ui = inb,  *Vi = inb + TOTAL,  *Di = inb + 2*TOTAL;
      float *Uo = outb, *Vo = outb + TOTAL, *Do_ = outb + 2*TOTAL;
      float2* S = (float2*)(inb + TOTAL);
      float*  Q = inb;
      advect_kernel_fb<<<TOTAL/256, 256, 0, stream>>>(Ui, Vi, Di, Uo, Vo, Do_, dtw);
      fft_rows_div_fb <<<BATCH*32, 256, 0, stream>>>(Uo, Vo, S);
      fft_cols_fb     <<<BATCH*32, 256, 0, stream>>>(S);
      fft_rows_inv_fb <<<BATCH*32, 256, 0, stream>>>(S, Q);
      correct_uv_fb   <<<TOTAL/256, 256, 0, stream>>>(Uo, Vo, Q);
      float* tmp = inb; inb = outb; outb = tmp;
    }
    write_out_k<<<TOTAL/256, 256, 0, stream>>>(inb, inb+TOTAL, inb+2*TOTAL, out, t, T);
  }
}